// Round 4
// baseline (457799.023 us; speedup 1.0000x reference)
//
#include <hip/hip_runtime.h>
#include <math.h>

#define T_STEPS 4096
#define HDIM    2048
#define KDIM    2048
#define NG      8192   // 4*H

typedef unsigned long long ull;

// ---------------- init: seed tagged buffers + leader slots ----------------
// hbuf/xcdbuf layout: ull [2][HDIM]; word = (tag<<32) | float_bits.
// Step-t readers read slot (t+1)&1 expecting tag t; step-t writers store
// tag t+1 into slot t&1. Seed: slot1 = {h0, tag 0}; slot0 = invalid tag.
__global__ void init_ws2(const float* __restrict__ h0,
                         ull* __restrict__ hbuf,      // [2][HDIM]
                         ull* __restrict__ xcdbuf,    // [8][2][HDIM]
                         unsigned* __restrict__ leaders) { // [8]
    int g = blockIdx.x * blockDim.x + threadIdx.x;
    union { float f; unsigned u; } cv;
    if (g < HDIM) {
        hbuf[g] = 0xFFFFFFFF00000000ull;
    } else if (g < 2 * HDIM) {
        cv.f = h0[g - HDIM];
        hbuf[g] = (ull)cv.u;                   // tag 0
    }
    int xg = g - 2 * HDIM;
    if (xg >= 0 && xg < 8 * 2 * HDIM) {
        int r = xg & (2 * HDIM - 1);
        if (r < HDIM) xcdbuf[xg] = 0xFFFFFFFF00000000ull;
        else { cv.f = h0[r - HDIM]; xcdbuf[xg] = (ull)cv.u; }
    }
    int lg = g - (2 * HDIM + 16 * HDIM);
    if (lg >= 0 && lg < 8) leaders[lg] = 0xFFFFFFFFu;
}

// ---------------- Phase 1: Y = X @ Wi + bias (fp32 tiled GEMM) ----------------
__global__ __launch_bounds__(256) void gemm_xwi(
    const float* __restrict__ X, const float* __restrict__ Wi,
    const float* __restrict__ bias, float* __restrict__ Y)
{
    __shared__ float As[16][65];
    __shared__ __align__(16) float Bs[16][64];
    const int tid = threadIdx.x;
    const int m0 = blockIdx.y * 64;
    const int n0 = blockIdx.x * 64;
    const int tx4 = (tid & 15) * 4;
    const int ty4 = (tid >> 4) * 4;
    const int am = tid >> 2, ak = (tid & 3) * 4;
    const int bk = tid >> 4, bn = (tid & 15) * 4;

    float acc[4][4];
#pragma unroll
    for (int i = 0; i < 4; ++i)
#pragma unroll
        for (int j = 0; j < 4; ++j) acc[i][j] = 0.f;

    for (int kt = 0; kt < KDIM; kt += 16) {
        float4 av = *reinterpret_cast<const float4*>(&X[(size_t)(m0 + am) * KDIM + kt + ak]);
        float4 bv = *reinterpret_cast<const float4*>(&Wi[(size_t)(kt + bk) * NG + n0 + bn]);
        __syncthreads();
        As[ak + 0][am] = av.x; As[ak + 1][am] = av.y;
        As[ak + 2][am] = av.z; As[ak + 3][am] = av.w;
        *reinterpret_cast<float4*>(&Bs[bk][bn]) = bv;
        __syncthreads();
#pragma unroll
        for (int k = 0; k < 16; ++k) {
            float a0 = As[k][ty4 + 0], a1 = As[k][ty4 + 1];
            float a2 = As[k][ty4 + 2], a3 = As[k][ty4 + 3];
            float4 b4 = *reinterpret_cast<const float4*>(&Bs[k][tx4]);
            acc[0][0] = fmaf(a0, b4.x, acc[0][0]); acc[0][1] = fmaf(a0, b4.y, acc[0][1]);
            acc[0][2] = fmaf(a0, b4.z, acc[0][2]); acc[0][3] = fmaf(a0, b4.w, acc[0][3]);
            acc[1][0] = fmaf(a1, b4.x, acc[1][0]); acc[1][1] = fmaf(a1, b4.y, acc[1][1]);
            acc[1][2] = fmaf(a1, b4.z, acc[1][2]); acc[1][3] = fmaf(a1, b4.w, acc[1][3]);
            acc[2][0] = fmaf(a2, b4.x, acc[2][0]); acc[2][1] = fmaf(a2, b4.y, acc[2][1]);
            acc[2][2] = fmaf(a2, b4.z, acc[2][2]); acc[2][3] = fmaf(a2, b4.w, acc[2][3]);
            acc[3][0] = fmaf(a3, b4.x, acc[3][0]); acc[3][1] = fmaf(a3, b4.y, acc[3][1]);
            acc[3][2] = fmaf(a3, b4.z, acc[3][2]); acc[3][3] = fmaf(a3, b4.w, acc[3][3]);
        }
    }
    float4 bb = *reinterpret_cast<const float4*>(&bias[n0 + tx4]);
#pragma unroll
    for (int i = 0; i < 4; ++i) {
        float4 o;
        o.x = acc[i][0] + bb.x; o.y = acc[i][1] + bb.y;
        o.z = acc[i][2] + bb.z; o.w = acc[i][3] + bb.w;
        *reinterpret_cast<float4*>(&Y[(size_t)(m0 + ty4 + i) * NG + n0 + tx4]) = o;
    }
}

// ---------------- fast activations ----------------
__device__ __forceinline__ float fsigm(float x) { return 1.f / (1.f + __expf(-x)); }
__device__ __forceinline__ float ftanh(float x) {
    float ax = fabsf(x);
    float e  = __expf(2.f * ax);
    float t  = (e - 1.f) / (e + 1.f);
    t = (ax > 15.f) ? 1.f : t;
    return copysignf(t, x);
}

// ---- sc0-only 4x8B load: bypass L1, served by the XCD-local L2 ----
__device__ __forceinline__ void ld4_sc0(const ull* p, ull& p0, ull& p1, ull& p2, ull& p3) {
    asm volatile(
        "global_load_dwordx2 %0, %4, off sc0\n\t"
        "global_load_dwordx2 %1, %4, off offset:8 sc0\n\t"
        "global_load_dwordx2 %2, %4, off offset:16 sc0\n\t"
        "global_load_dwordx2 %3, %4, off offset:24 sc0\n\t"
        "s_waitcnt vmcnt(0)"
        : "=&v"(p0), "=&v"(p1), "=&v"(p2), "=&v"(p3)
        : "v"(p) : "memory");
}
// ---- plain 4x8B store: write-allocates in the storing CU's XCD L2 ----
__device__ __forceinline__ void st4_plain(ull* p, ull a, ull b, ull c, ull d) {
    asm volatile(
        "global_store_dwordx2 %0, %1, off\n\t"
        "global_store_dwordx2 %0, %2, off offset:8\n\t"
        "global_store_dwordx2 %0, %3, off offset:16\n\t"
        "global_store_dwordx2 %0, %4, off offset:24"
        :: "v"(p), "v"(a), "v"(b), "v"(c), "v"(d) : "memory");
}

// ---------------- Phase 2: persistent recurrent kernel ----------------
// 256 blocks x 512 threads, cooperative, 1 block/CU.
// Per-XCD leader polls global (MALL) tagged hbuf and re-publishes into an
// XCD-local buffer via plain stores (allocate in local L2); followers poll
// that buffer with sc0-only loads. 32x fewer MALL readers than round 3.
__global__ __launch_bounds__(512, 2) void lstm_persistent(
    const float* __restrict__ Y,     // [T][NG]
    const float* __restrict__ c0,
    const float* __restrict__ Wh,    // [K][NG]
    ull* __restrict__ hbuf,          // [2][HDIM] global tagged ping-pong
    ull* __restrict__ xcdbuf,        // [8][2][HDIM]
    unsigned* __restrict__ leaders,  // [8]
    float* __restrict__ out)         // [c_f][h_f][ys]
{
    const int b    = blockIdx.x;
    const int tid  = threadIdx.x;
    const int lane = tid & 63;
    const int w    = tid >> 6;
    const int gg   = w >> 1;
    const int hg   = w & 1;
    const int nbase = (gg << 11) + (b << 3) + (hg << 2);

    __shared__ float4 hlds4[HDIM / 4];
    __shared__ float gates[32];
    __shared__ float c_s[8];
    __shared__ float hlast[8];
    __shared__ int s_lead, s_xcd;

    // ---- leader election (once) ----
    if (tid == 0) {
        unsigned x;
        asm volatile("s_getreg_b32 %0, hwreg(HW_REG_XCC_ID, 0, 4)" : "=s"(x));
        x &= 7u;
        unsigned old = atomicCAS(&leaders[x], 0xFFFFFFFFu, (unsigned)b);
        s_lead = (old == 0xFFFFFFFFu) ? 1 : 0;
        s_xcd  = (int)x;
    }

    // ---- load weight slice once, force register residency ----
    float4 wreg[32];
#pragma unroll
    for (int j = 0; j < 8; ++j)
#pragma unroll
        for (int m = 0; m < 4; ++m) {
            const size_t k = (size_t)(4 * lane + 256 * j + m);
            wreg[j * 4 + m] = *reinterpret_cast<const float4*>(&Wh[k * NG + nbase]);
        }
#pragma unroll
    for (int i = 0; i < 32; ++i) {
        asm volatile("" : "+v"(wreg[i].x), "+v"(wreg[i].y),
                          "+v"(wreg[i].z), "+v"(wreg[i].w));
    }

    if (tid < 8) c_s[tid] = c0[b * 8 + tid];
    __syncthreads();
    const int  isLeader = s_lead;   // block-uniform
    const int  myXcd    = s_xcd;
    ull* myXbuf = xcdbuf + (size_t)myXcd * 2 * HDIM;

    for (int t = 0; t < T_STEPS; ++t) {
        // ---- Y prefetch (hidden under the poll) ----
        float yv = 0.f;
        if (lane < 4) yv = Y[(size_t)t * NG + nbase + lane];

        const size_t slotOff = (size_t)((t + 1) & 1) * HDIM;
        const ull tg = (ull)(unsigned)t;
        ull p0, p1, p2, p3;

        if (isLeader) {
            // ---- leader: poll global (MALL) then forward into local L2 ----
            const ull* hs = hbuf + slotOff + 4 * tid;
            for (;;) {
                p0 = __hip_atomic_load(hs + 0, __ATOMIC_RELAXED, __HIP_MEMORY_SCOPE_SYSTEM);
                p1 = __hip_atomic_load(hs + 1, __ATOMIC_RELAXED, __HIP_MEMORY_SCOPE_SYSTEM);
                p2 = __hip_atomic_load(hs + 2, __ATOMIC_RELAXED, __HIP_MEMORY_SCOPE_SYSTEM);
                p3 = __hip_atomic_load(hs + 3, __ATOMIC_RELAXED, __HIP_MEMORY_SCOPE_SYSTEM);
                if (((p0 >> 32) == tg) & ((p1 >> 32) == tg) &
                    ((p2 >> 32) == tg) & ((p3 >> 32) == tg)) break;
            }
            st4_plain(myXbuf + slotOff + 4 * tid, p0, p1, p2, p3);
        } else {
            // ---- follower: poll XCD-local copy (sc0 -> L2-served) ----
            const ull* xs = myXbuf + slotOff + 4 * tid;
            bool ok = false;
            for (int spins = 0; spins < 512; ++spins) {
                ld4_sc0(xs, p0, p1, p2, p3);
                if (((p0 >> 32) == tg) & ((p1 >> 32) == tg) &
                    ((p2 >> 32) == tg) & ((p3 >> 32) == tg)) { ok = true; break; }
            }
            if (!ok) {  // deadlock insurance: global hbuf is the source of truth
                const ull* hs = hbuf + slotOff + 4 * tid;
                for (;;) {
                    p0 = __hip_atomic_load(hs + 0, __ATOMIC_RELAXED, __HIP_MEMORY_SCOPE_SYSTEM);
                    p1 = __hip_atomic_load(hs + 1, __ATOMIC_RELAXED, __HIP_MEMORY_SCOPE_SYSTEM);
                    p2 = __hip_atomic_load(hs + 2, __ATOMIC_RELAXED, __HIP_MEMORY_SCOPE_SYSTEM);
                    p3 = __hip_atomic_load(hs + 3, __ATOMIC_RELAXED, __HIP_MEMORY_SCOPE_SYSTEM);
                    if (((p0 >> 32) == tg) & ((p1 >> 32) == tg) &
                        ((p2 >> 32) == tg) & ((p3 >> 32) == tg)) break;
                    __builtin_amdgcn_s_sleep(1);
                }
            }
        }
        union { unsigned u; float f; } c0u, c1u, c2u, c3u;
        c0u.u = (unsigned)p0; c1u.u = (unsigned)p1;
        c2u.u = (unsigned)p2; c3u.u = (unsigned)p3;
        float4 hv; hv.x = c0u.f; hv.y = c1u.f; hv.z = c2u.f; hv.w = c3u.f;
        hlds4[tid] = hv;
        __syncthreads();

        // ---- 128 FMAs on register-resident weights ----
        float4 acc; acc.x = acc.y = acc.z = acc.w = 0.f;
#pragma unroll
        for (int j = 0; j < 8; ++j) {
            float4 h4 = hlds4[lane + 64 * j];
            float4 w0 = wreg[4 * j + 0], w1 = wreg[4 * j + 1];
            float4 w2 = wreg[4 * j + 2], w3 = wreg[4 * j + 3];
            acc.x = fmaf(h4.x, w0.x, acc.x); acc.x = fmaf(h4.y, w1.x, acc.x);
            acc.x = fmaf(h4.z, w2.x, acc.x); acc.x = fmaf(h4.w, w3.x, acc.x);
            acc.y = fmaf(h4.x, w0.y, acc.y); acc.y = fmaf(h4.y, w1.y, acc.y);
            acc.y = fmaf(h4.z, w2.y, acc.y); acc.y = fmaf(h4.w, w3.y, acc.y);
            acc.z = fmaf(h4.x, w0.z, acc.z); acc.z = fmaf(h4.y, w1.z, acc.z);
            acc.z = fmaf(h4.z, w2.z, acc.z); acc.z = fmaf(h4.w, w3.z, acc.z);
            acc.w = fmaf(h4.x, w0.w, acc.w); acc.w = fmaf(h4.y, w1.w, acc.w);
            acc.w = fmaf(h4.z, w2.w, acc.w); acc.w = fmaf(h4.w, w3.w, acc.w);
        }
#pragma unroll
        for (int off = 32; off >= 1; off >>= 1) {
            acc.x += __shfl_xor(acc.x, off);
            acc.y += __shfl_xor(acc.y, off);
            acc.z += __shfl_xor(acc.z, off);
            acc.w += __shfl_xor(acc.w, off);
        }
        if (lane < 4) {
            float v = (lane == 0) ? acc.x : (lane == 1) ? acc.y
                    : (lane == 2) ? acc.z : acc.w;
            gates[gg * 8 + hg * 4 + lane] = v + yv;
        }
        __syncthreads();

        // ---- epilogue: 8 h outputs; publish tagged word to global hbuf ----
        if (tid < 8) {
            float iv = gates[0 * 8 + tid];
            float fv = gates[1 * 8 + tid];
            float gv = gates[2 * 8 + tid];
            float ov = gates[3 * 8 + tid];
            float cn = fsigm(fv) * c_s[tid] + fsigm(iv) * ftanh(gv);
            float hn = fsigm(ov) * ftanh(cn);
            c_s[tid] = cn;
            hlast[tid] = hn;
            __builtin_nontemporal_store(hn, &out[2 * HDIM + (size_t)t * HDIM + b * 8 + tid]);
            union { float f; unsigned u; } cv; cv.f = hn;
            ull pk = ((ull)(unsigned)(t + 1) << 32) | (ull)cv.u;
            __hip_atomic_store(hbuf + (size_t)(t & 1) * HDIM + b * 8 + tid, pk,
                               __ATOMIC_RELAXED, __HIP_MEMORY_SCOPE_SYSTEM);
        }
        // No device-wide barrier: tag dataflow is the barrier; 2 slots suffice
        // (a tag t+2 word existing implies every block consumed all tag-t words,
        //  so xcdbuf slot reuse by the leader is also safe).
    }

    if (tid < 8) {
        out[b * 8 + tid]        = c_s[tid];   // c_f
        out[HDIM + b * 8 + tid] = hlast[tid]; // h_f
    }
}

// ---------------- launch ----------------
extern "C" void kernel_launch(void* const* d_in, const int* in_sizes, int n_in,
                              void* d_out, int out_size, void* d_ws, size_t ws_size,
                              hipStream_t stream) {
    const float* x   = (const float*)d_in[0];
    const float* c0  = (const float*)d_in[1];
    const float* h0  = (const float*)d_in[2];
    const float* Wi  = (const float*)d_in[3];
    const float* Wh  = (const float*)d_in[4];
    const float* bia = (const float*)d_in[5];
    float* out = (float*)d_out;

    char* base = (char*)d_ws;
    float* Y = (float*)base;                                   // 128 MiB
    base += (size_t)T_STEPS * NG * sizeof(float);
    ull* hbuf = (ull*)base;          base += 2 * HDIM * sizeof(ull);     // 32 KiB
    ull* xcdbuf = (ull*)base;        base += 8 * 2 * HDIM * sizeof(ull); // 256 KiB
    unsigned* leaders = (unsigned*)base;                                  // 32 B

    const int initN = 2 * HDIM + 16 * HDIM + 8;
    hipLaunchKernelGGL(init_ws2, dim3((initN + 511) / 512), dim3(512), 0, stream,
                       h0, hbuf, xcdbuf, leaders);
    hipLaunchKernelGGL(gemm_xwi, dim3(NG / 64, T_STEPS / 64), dim3(256), 0, stream,
                       x, Wi, bia, Y);

    void* args[] = { (void*)&Y, (void*)&c0, (void*)&Wh, (void*)&hbuf,
                     (void*)&xcdbuf, (void*)&leaders, (void*)&out };
    hipLaunchCooperativeKernel((const void*)lstm_persistent, dim3(256), dim3(512),
                               args, 0, stream);
}

// Round 5
// 51640.924 us; speedup vs baseline: 8.8650x; 8.8650x over previous
//
#include <hip/hip_runtime.h>
#include <math.h>

#define T_STEPS 4096
#define HDIM    2048
#define KDIM    2048
#define NG      8192      // 4*H
#define TAG_STRIDE 16     // uints: one 64B line per producer tag (avoid line hotspot)

typedef unsigned long long ull;

// ---------------- init ----------------
// htag[2][256*TAG_STRIDE]: ready tag per (slot, producer block). Value t+1 in
// slot t&1 means "h for step t+1 available". Readers at step t poll slot
// (t+1)&1 for value t. Seed: slot1 tags = 0 (h0 ready), slot0 = invalid.
// hdata[2][HDIM]: plain fp32 h values, slot1 = h0.
__global__ void init_ws3(const float* __restrict__ h0,
                         unsigned* __restrict__ htag,   // [2][256*TAG_STRIDE]
                         float* __restrict__ hdata) {   // [2][HDIM]
    int g = blockIdx.x * blockDim.x + threadIdx.x;
    if (g < 2 * 256 * TAG_STRIDE) {
        unsigned v = 0xFFFFFFFFu;
        if (g >= 256 * TAG_STRIDE && ((g - 256 * TAG_STRIDE) % TAG_STRIDE) == 0)
            v = 0u;   // slot1, tag word
        htag[g] = v;
    }
    int d = g - 2 * 256 * TAG_STRIDE;
    if (d >= 0 && d < 2 * HDIM)
        hdata[d] = (d < HDIM) ? 0.f : h0[d - HDIM];
}

// ---------------- Phase 1: Y = X @ Wi + bias (fp32 tiled GEMM) ----------------
__global__ __launch_bounds__(256) void gemm_xwi(
    const float* __restrict__ X, const float* __restrict__ Wi,
    const float* __restrict__ bias, float* __restrict__ Y)
{
    __shared__ float As[16][65];
    __shared__ __align__(16) float Bs[16][64];
    const int tid = threadIdx.x;
    const int m0 = blockIdx.y * 64;
    const int n0 = blockIdx.x * 64;
    const int tx4 = (tid & 15) * 4;
    const int ty4 = (tid >> 4) * 4;
    const int am = tid >> 2, ak = (tid & 3) * 4;
    const int bk = tid >> 4, bn = (tid & 15) * 4;

    float acc[4][4];
#pragma unroll
    for (int i = 0; i < 4; ++i)
#pragma unroll
        for (int j = 0; j < 4; ++j) acc[i][j] = 0.f;

    for (int kt = 0; kt < KDIM; kt += 16) {
        float4 av = *reinterpret_cast<const float4*>(&X[(size_t)(m0 + am) * KDIM + kt + ak]);
        float4 bv = *reinterpret_cast<const float4*>(&Wi[(size_t)(kt + bk) * NG + n0 + bn]);
        __syncthreads();
        As[ak + 0][am] = av.x; As[ak + 1][am] = av.y;
        As[ak + 2][am] = av.z; As[ak + 3][am] = av.w;
        *reinterpret_cast<float4*>(&Bs[bk][bn]) = bv;
        __syncthreads();
#pragma unroll
        for (int k = 0; k < 16; ++k) {
            float a0 = As[k][ty4 + 0], a1 = As[k][ty4 + 1];
            float a2 = As[k][ty4 + 2], a3 = As[k][ty4 + 3];
            float4 b4 = *reinterpret_cast<const float4*>(&Bs[k][tx4]);
            acc[0][0] = fmaf(a0, b4.x, acc[0][0]); acc[0][1] = fmaf(a0, b4.y, acc[0][1]);
            acc[0][2] = fmaf(a0, b4.z, acc[0][2]); acc[0][3] = fmaf(a0, b4.w, acc[0][3]);
            acc[1][0] = fmaf(a1, b4.x, acc[1][0]); acc[1][1] = fmaf(a1, b4.y, acc[1][1]);
            acc[1][2] = fmaf(a1, b4.z, acc[1][2]); acc[1][3] = fmaf(a1, b4.w, acc[1][3]);
            acc[2][0] = fmaf(a2, b4.x, acc[2][0]); acc[2][1] = fmaf(a2, b4.y, acc[2][1]);
            acc[2][2] = fmaf(a2, b4.z, acc[2][2]); acc[2][3] = fmaf(a2, b4.w, acc[2][3]);
            acc[3][0] = fmaf(a3, b4.x, acc[3][0]); acc[3][1] = fmaf(a3, b4.y, acc[3][1]);
            acc[3][2] = fmaf(a3, b4.z, acc[3][2]); acc[3][3] = fmaf(a3, b4.w, acc[3][3]);
        }
    }
    float4 bb = *reinterpret_cast<const float4*>(&bias[n0 + tx4]);
#pragma unroll
    for (int i = 0; i < 4; ++i) {
        float4 o;
        o.x = acc[i][0] + bb.x; o.y = acc[i][1] + bb.y;
        o.z = acc[i][2] + bb.z; o.w = acc[i][3] + bb.w;
        *reinterpret_cast<float4*>(&Y[(size_t)(m0 + ty4 + i) * NG + n0 + tx4]) = o;
    }
}

// ---------------- fast activations ----------------
__device__ __forceinline__ float fsigm(float x) { return 1.f / (1.f + __expf(-x)); }
__device__ __forceinline__ float ftanh(float x) {
    float ax = fabsf(x);
    float e  = __expf(2.f * ax);
    float t  = (e - 1.f) / (e + 1.f);
    t = (ax > 15.f) ? 1.f : t;
    return copysignf(t, x);
}

// ---------------- Phase 2: persistent recurrent kernel ----------------
// 256 blocks x 512 threads, cooperative, 1 block/CU. Flat MALL-coherent
// protocol (round-4's XCD-local forwarding is unsound: cross-XCD L2 dirty
// lines are invisible; never depend on block->XCD placement).
// Per step: wave w polls 32 line-padded producer tags -> single-shot loads
// its 256-float chunk -> LDS + flag; consumes chunks cyclically as flags
// arrive (compute overlaps late producers). One __syncthreads per step.
__global__ __launch_bounds__(512, 2) void lstm_persistent(
    const float* __restrict__ Y,     // [T][NG]
    const float* __restrict__ c0,
    const float* __restrict__ Wh,    // [K][NG]
    float* __restrict__ hdata,       // [2][HDIM]
    unsigned* __restrict__ htag,     // [2][256*TAG_STRIDE]
    float* __restrict__ out)         // [c_f][h_f][ys]
{
    const int b    = blockIdx.x;
    const int tid  = threadIdx.x;
    const int lane = tid & 63;
    const int w    = tid >> 6;       // 0..7 (also: chunk this wave stages)
    const int gg   = w >> 1;
    const int hg   = w & 1;
    const int nbase = (gg << 11) + (b << 3) + (hg << 2);

    __shared__ float4 hlds4[HDIM / 4];   // 8 KiB staging
    __shared__ float gates[2][32];       // double-buffered epilogue handoff
    __shared__ float c_s[8];
    __shared__ float hlast[8];
    __shared__ unsigned chflag[8];       // LDS per-chunk ready flags (= step)

    // ---- load weight slice once, force register residency ----
    float4 wreg[32];
#pragma unroll
    for (int j = 0; j < 8; ++j)
#pragma unroll
        for (int m = 0; m < 4; ++m) {
            const size_t k = (size_t)(4 * lane + 256 * j + m);
            wreg[j * 4 + m] = *reinterpret_cast<const float4*>(&Wh[k * NG + nbase]);
        }
#pragma unroll
    for (int i = 0; i < 32; ++i) {
        asm volatile("" : "+v"(wreg[i].x), "+v"(wreg[i].y),
                          "+v"(wreg[i].z), "+v"(wreg[i].w));
    }

    if (tid < 8) { c_s[tid] = c0[b * 8 + tid]; chflag[tid] = 0xFFFFFFFFu; }
    __syncthreads();

    for (int t = 0; t < T_STEPS; ++t) {
        const int rs = (t + 1) & 1;          // read slot
        const unsigned tg = (unsigned)t;

        // Y prefetch (hidden under the tag wait)
        float yv = 0.f;
        if (lane < 4) yv = Y[(size_t)t * NG + nbase + lane];

        // ---- stage chunk w: lanes 0..31 poll 32 producer tags ----
        {
            const unsigned* tp = htag + (size_t)rs * 256 * TAG_STRIDE
                                 + (size_t)(32 * w + (lane & 31)) * TAG_STRIDE;
            for (;;) {
                unsigned v = tg;
                if (lane < 32)
                    v = __hip_atomic_load(tp, __ATOMIC_RELAXED, __HIP_MEMORY_SCOPE_SYSTEM);
                if (__all(v == tg)) break;
                __builtin_amdgcn_s_sleep(1);
            }
            // single-shot chunk data load (16B/lane, MALL-coherent)
            const float* dp = hdata + (size_t)rs * HDIM + 256 * w + 4 * lane;
            float4 dv;
            asm volatile("global_load_dwordx4 %0, %1, off sc0 sc1\n\t"
                         "s_waitcnt vmcnt(0)"
                         : "=v"(dv) : "v"(dp) : "memory");
            hlds4[64 * w + lane] = dv;
            __hip_atomic_store(&chflag[w], tg, __ATOMIC_RELEASE,
                               __HIP_MEMORY_SCOPE_WORKGROUP);
        }

        // ---- consume chunks cyclically (own chunk first: flag already set) ----
        float4 acc; acc.x = acc.y = acc.z = acc.w = 0.f;
#pragma unroll
        for (int jj = 0; jj < 8; ++jj) {
            const int j = (w + jj) & 7;
            while (__hip_atomic_load(&chflag[j], __ATOMIC_ACQUIRE,
                                     __HIP_MEMORY_SCOPE_WORKGROUP) != tg)
                __builtin_amdgcn_s_sleep(1);
            float4 h4 = hlds4[lane + 64 * j];
            float4 w0 = wreg[4 * j + 0], w1 = wreg[4 * j + 1];
            float4 w2 = wreg[4 * j + 2], w3 = wreg[4 * j + 3];
            acc.x = fmaf(h4.x, w0.x, acc.x); acc.x = fmaf(h4.y, w1.x, acc.x);
            acc.x = fmaf(h4.z, w2.x, acc.x); acc.x = fmaf(h4.w, w3.x, acc.x);
            acc.y = fmaf(h4.x, w0.y, acc.y); acc.y = fmaf(h4.y, w1.y, acc.y);
            acc.y = fmaf(h4.z, w2.y, acc.y); acc.y = fmaf(h4.w, w3.y, acc.y);
            acc.z = fmaf(h4.x, w0.z, acc.z); acc.z = fmaf(h4.y, w1.z, acc.z);
            acc.z = fmaf(h4.z, w2.z, acc.z); acc.z = fmaf(h4.w, w3.z, acc.z);
            acc.w = fmaf(h4.x, w0.w, acc.w); acc.w = fmaf(h4.y, w1.w, acc.w);
            acc.w = fmaf(h4.z, w2.w, acc.w); acc.w = fmaf(h4.w, w3.w, acc.w);
        }
#pragma unroll
        for (int off = 32; off >= 1; off >>= 1) {
            acc.x += __shfl_xor(acc.x, off);
            acc.y += __shfl_xor(acc.y, off);
            acc.z += __shfl_xor(acc.z, off);
            acc.w += __shfl_xor(acc.w, off);
        }
        if (lane < 4) {
            float v = (lane == 0) ? acc.x : (lane == 1) ? acc.y
                    : (lane == 2) ? acc.z : acc.w;
            gates[t & 1][gg * 8 + hg * 4 + lane] = v + yv;
        }
        __syncthreads();   // ensures: gates ready; all LDS h-reads of step t done

        // ---- epilogue (wave 0 only; others run ahead into step t+1) ----
        if (tid < 8) {
            float iv = gates[t & 1][0 * 8 + tid];
            float fv = gates[t & 1][1 * 8 + tid];
            float gv = gates[t & 1][2 * 8 + tid];
            float ov = gates[t & 1][3 * 8 + tid];
            float cn = fsigm(fv) * c_s[tid] + fsigm(iv) * ftanh(gv);
            float hn = fsigm(ov) * ftanh(cn);
            c_s[tid] = cn;
            hlast[tid] = hn;
            const int ws_ = t & 1;
            // data first, then (after vmcnt drain = release) the ready tag
            __hip_atomic_store(&hdata[(size_t)ws_ * HDIM + b * 8 + tid], hn,
                               __ATOMIC_RELAXED, __HIP_MEMORY_SCOPE_SYSTEM);
            asm volatile("s_waitcnt vmcnt(0)" ::: "memory");
            if (tid == 0)
                __hip_atomic_store(&htag[(size_t)ws_ * 256 * TAG_STRIDE + (size_t)b * TAG_STRIDE],
                                   (unsigned)(t + 1),
                                   __ATOMIC_RELAXED, __HIP_MEMORY_SCOPE_SYSTEM);
            __builtin_nontemporal_store(hn, &out[2 * HDIM + (size_t)t * HDIM + b * 8 + tid]);
        }
    }

    if (tid < 8) {
        out[b * 8 + tid]        = c_s[tid];   // c_f
        out[HDIM + b * 8 + tid] = hlast[tid]; // h_f
    }
}

// ---------------- launch ----------------
extern "C" void kernel_launch(void* const* d_in, const int* in_sizes, int n_in,
                              void* d_out, int out_size, void* d_ws, size_t ws_size,
                              hipStream_t stream) {
    const float* x   = (const float*)d_in[0];
    const float* c0  = (const float*)d_in[1];
    const float* h0  = (const float*)d_in[2];
    const float* Wi  = (const float*)d_in[3];
    const float* Wh  = (const float*)d_in[4];
    const float* bia = (const float*)d_in[5];
    float* out = (float*)d_out;

    char* base = (char*)d_ws;
    float* Y = (float*)base;                                  // 128 MiB
    base += (size_t)T_STEPS * NG * sizeof(float);
    unsigned* htag = (unsigned*)base;                         // 32 KiB
    base += 2 * 256 * TAG_STRIDE * sizeof(unsigned);
    float* hdata = (float*)base;                              // 16 KiB

    const int initN = 2 * 256 * TAG_STRIDE + 2 * HDIM;
    hipLaunchKernelGGL(init_ws3, dim3((initN + 511) / 512), dim3(512), 0, stream,
                       h0, htag, hdata);
    hipLaunchKernelGGL(gemm_xwi, dim3(NG / 64, T_STEPS / 64), dim3(256), 0, stream,
                       x, Wi, bia, Y);

    void* args[] = { (void*)&Y, (void*)&c0, (void*)&Wh,
                     (void*)&hdata, (void*)&htag, (void*)&out };
    hipLaunchCooperativeKernel((const void*)lstm_persistent, dim3(256), dim3(512),
                               args, 0, stream);
}

// Round 6
// 15284.181 us; speedup vs baseline: 29.9525x; 3.3787x over previous
//
#include <hip/hip_runtime.h>
#include <math.h>

#define T_STEPS 4096
#define HDIM    2048
#define KDIM    2048
#define NG      8192      // 4*H
#define CTR_STRIDE 16     // uints: one 64B line per counter

typedef unsigned long long ull;

// ---------------- init ----------------
// ctr[8] (64B apart): monotonic. Seeded to 32 (= "h0 published" credit from
// each counter's 32 blocks). Step-t consumers wait ctr[g] >= 32*(t+1).
// hdata[2][HDIM]: plain fp32 h values; slot1 = h0 (step 0 reads slot 1).
__global__ void init_ws4(const float* __restrict__ h0,
                         unsigned* __restrict__ ctr,    // [8*CTR_STRIDE]
                         float* __restrict__ hdata) {   // [2][HDIM]
    int g = blockIdx.x * blockDim.x + threadIdx.x;
    if (g < 8 * CTR_STRIDE) ctr[g] = ((g % CTR_STRIDE) == 0) ? 32u : 0u;
    int d = g - 8 * CTR_STRIDE;
    if (d >= 0 && d < 2 * HDIM)
        hdata[d] = (d < HDIM) ? 0.f : h0[d - HDIM];
}

// ---------------- Phase 1: Y = X @ Wi + bias (fp32 tiled GEMM) ----------------
__global__ __launch_bounds__(256) void gemm_xwi(
    const float* __restrict__ X, const float* __restrict__ Wi,
    const float* __restrict__ bias, float* __restrict__ Y)
{
    __shared__ float As[16][65];
    __shared__ __align__(16) float Bs[16][64];
    const int tid = threadIdx.x;
    const int m0 = blockIdx.y * 64;
    const int n0 = blockIdx.x * 64;
    const int tx4 = (tid & 15) * 4;
    const int ty4 = (tid >> 4) * 4;
    const int am = tid >> 2, ak = (tid & 3) * 4;
    const int bk = tid >> 4, bn = (tid & 15) * 4;

    float acc[4][4];
#pragma unroll
    for (int i = 0; i < 4; ++i)
#pragma unroll
        for (int j = 0; j < 4; ++j) acc[i][j] = 0.f;

    for (int kt = 0; kt < KDIM; kt += 16) {
        float4 av = *reinterpret_cast<const float4*>(&X[(size_t)(m0 + am) * KDIM + kt + ak]);
        float4 bv = *reinterpret_cast<const float4*>(&Wi[(size_t)(kt + bk) * NG + n0 + bn]);
        __syncthreads();
        As[ak + 0][am] = av.x; As[ak + 1][am] = av.y;
        As[ak + 2][am] = av.z; As[ak + 3][am] = av.w;
        *reinterpret_cast<float4*>(&Bs[bk][bn]) = bv;
        __syncthreads();
#pragma unroll
        for (int k = 0; k < 16; ++k) {
            float a0 = As[k][ty4 + 0], a1 = As[k][ty4 + 1];
            float a2 = As[k][ty4 + 2], a3 = As[k][ty4 + 3];
            float4 b4 = *reinterpret_cast<const float4*>(&Bs[k][tx4]);
            acc[0][0] = fmaf(a0, b4.x, acc[0][0]); acc[0][1] = fmaf(a0, b4.y, acc[0][1]);
            acc[0][2] = fmaf(a0, b4.z, acc[0][2]); acc[0][3] = fmaf(a0, b4.w, acc[0][3]);
            acc[1][0] = fmaf(a1, b4.x, acc[1][0]); acc[1][1] = fmaf(a1, b4.y, acc[1][1]);
            acc[1][2] = fmaf(a1, b4.z, acc[1][2]); acc[1][3] = fmaf(a1, b4.w, acc[1][3]);
            acc[2][0] = fmaf(a2, b4.x, acc[2][0]); acc[2][1] = fmaf(a2, b4.y, acc[2][1]);
            acc[2][2] = fmaf(a2, b4.z, acc[2][2]); acc[2][3] = fmaf(a2, b4.w, acc[2][3]);
            acc[3][0] = fmaf(a3, b4.x, acc[3][0]); acc[3][1] = fmaf(a3, b4.y, acc[3][1]);
            acc[3][2] = fmaf(a3, b4.z, acc[3][2]); acc[3][3] = fmaf(a3, b4.w, acc[3][3]);
        }
    }
    float4 bb = *reinterpret_cast<const float4*>(&bias[n0 + tx4]);
#pragma unroll
    for (int i = 0; i < 4; ++i) {
        float4 o;
        o.x = acc[i][0] + bb.x; o.y = acc[i][1] + bb.y;
        o.z = acc[i][2] + bb.z; o.w = acc[i][3] + bb.w;
        *reinterpret_cast<float4*>(&Y[(size_t)(m0 + ty4 + i) * NG + n0 + tx4]) = o;
    }
}

// ---------------- fast activations ----------------
__device__ __forceinline__ float fsigm(float x) { return 1.f / (1.f + __expf(-x)); }
__device__ __forceinline__ float ftanh(float x) {
    float ax = fabsf(x);
    float e  = __expf(2.f * ax);
    float t  = (e - 1.f) / (e + 1.f);
    t = (ax > 15.f) ? 1.f : t;
    return copysignf(t, x);
}

// ---------------- Phase 2: persistent recurrent kernel ----------------
// 256 blocks x 512 threads, cooperative, 1 block/CU.
// Sync: producers atomicAdd one of 8 line-spaced SYSTEM counters after a
// vmcnt-drained data publish (release at the MALL). Per block, ONLY wave 0
// polls (lanes 0-7, one counter each); waves 1-7 spin on an LDS flag.
// Chip-wide poll lanes: 2048 (vs 65536 in round 5 -> the FETCH storm).
// Data: single-shot sc0sc1 1KB/wave chunk loads after the flag.
__global__ __launch_bounds__(512, 2) void lstm_persistent(
    const float* __restrict__ Y,     // [T][NG]
    const float* __restrict__ c0,
    const float* __restrict__ Wh,    // [K][NG]
    float* __restrict__ hdata,       // [2][HDIM]
    unsigned* __restrict__ ctr,      // [8*CTR_STRIDE]
    float* __restrict__ out)         // [c_f][h_f][ys]
{
    const int b    = blockIdx.x;
    const int tid  = threadIdx.x;
    const int lane = tid & 63;
    const int w    = tid >> 6;       // 0..7 (= chunk this wave stages)
    const int gg   = w >> 1;
    const int hg   = w & 1;
    const int nbase = (gg << 11) + (b << 3) + (hg << 2);

    __shared__ float4 hlds4[HDIM / 4];   // 8 KiB staging
    __shared__ float gates[32];
    __shared__ float c_s[8];
    __shared__ float hlast[8];
    __shared__ unsigned ldsflag;

    // ---- load weight slice once, force register residency ----
    float4 wreg[32];
#pragma unroll
    for (int j = 0; j < 8; ++j)
#pragma unroll
        for (int m = 0; m < 4; ++m) {
            const size_t k = (size_t)(4 * lane + 256 * j + m);
            wreg[j * 4 + m] = *reinterpret_cast<const float4*>(&Wh[k * NG + nbase]);
        }
#pragma unroll
    for (int i = 0; i < 32; ++i) {
        asm volatile("" : "+v"(wreg[i].x), "+v"(wreg[i].y),
                          "+v"(wreg[i].z), "+v"(wreg[i].w));
    }

    if (tid < 8) c_s[tid] = c0[b * 8 + tid];
    if (tid == 0) ldsflag = 0xFFFFFFFFu;
    __syncthreads();

    for (int t = 0; t < T_STEPS; ++t) {
        const int rs = (t + 1) & 1;          // read slot (h input of step t)
        const unsigned target = 32u * (unsigned)(t + 1);

        // Y prefetch (hidden under the wait)
        float yv = 0.f;
        if (lane < 4) yv = Y[(size_t)t * NG + nbase + lane];

        // ---- barrier detect: wave 0 polls 8 counters; others spin on LDS ----
        if (w == 0) {
            const unsigned* cp = ctr + (size_t)(lane & 7) * CTR_STRIDE;
            for (;;) {
                unsigned v = target;
                if (lane < 8)
                    v = __hip_atomic_load(cp, __ATOMIC_RELAXED, __HIP_MEMORY_SCOPE_SYSTEM);
                if (__all(v >= target)) break;
                __builtin_amdgcn_s_sleep(1);
            }
            if (lane == 0)
                __hip_atomic_store(&ldsflag, (unsigned)t, __ATOMIC_RELEASE,
                                   __HIP_MEMORY_SCOPE_WORKGROUP);
        } else {
            while (__hip_atomic_load(&ldsflag, __ATOMIC_ACQUIRE,
                                     __HIP_MEMORY_SCOPE_WORKGROUP) != (unsigned)t)
                __builtin_amdgcn_s_sleep(1);
        }

        // ---- single-shot chunk data load (1KB per wave, MALL-coherent) ----
        {
            const float* dp = hdata + (size_t)rs * HDIM + 256 * w + 4 * lane;
            float4 dv;
            asm volatile("global_load_dwordx4 %0, %1, off sc0 sc1\n\t"
                         "s_waitcnt vmcnt(0)"
                         : "=v"(dv) : "v"(dp) : "memory");
            hlds4[64 * w + lane] = dv;
        }
        __syncthreads();   // all 8 chunks staged

        // ---- 128 FMAs on register-resident weights ----
        float4 acc; acc.x = acc.y = acc.z = acc.w = 0.f;
#pragma unroll
        for (int j = 0; j < 8; ++j) {
            float4 h4 = hlds4[lane + 64 * j];
            float4 w0 = wreg[4 * j + 0], w1 = wreg[4 * j + 1];
            float4 w2 = wreg[4 * j + 2], w3 = wreg[4 * j + 3];
            acc.x = fmaf(h4.x, w0.x, acc.x); acc.x = fmaf(h4.y, w1.x, acc.x);
            acc.x = fmaf(h4.z, w2.x, acc.x); acc.x = fmaf(h4.w, w3.x, acc.x);
            acc.y = fmaf(h4.x, w0.y, acc.y); acc.y = fmaf(h4.y, w1.y, acc.y);
            acc.y = fmaf(h4.z, w2.y, acc.y); acc.y = fmaf(h4.w, w3.y, acc.y);
            acc.z = fmaf(h4.x, w0.z, acc.z); acc.z = fmaf(h4.y, w1.z, acc.z);
            acc.z = fmaf(h4.z, w2.z, acc.z); acc.z = fmaf(h4.w, w3.z, acc.z);
            acc.w = fmaf(h4.x, w0.w, acc.w); acc.w = fmaf(h4.y, w1.w, acc.w);
            acc.w = fmaf(h4.z, w2.w, acc.w); acc.w = fmaf(h4.w, w3.w, acc.w);
        }
#pragma unroll
        for (int off = 32; off >= 1; off >>= 1) {
            acc.x += __shfl_xor(acc.x, off);
            acc.y += __shfl_xor(acc.y, off);
            acc.z += __shfl_xor(acc.z, off);
            acc.w += __shfl_xor(acc.w, off);
        }
        if (lane < 4) {
            float v = (lane == 0) ? acc.x : (lane == 1) ? acc.y
                    : (lane == 2) ? acc.z : acc.w;
            gates[gg * 8 + hg * 4 + lane] = v + yv;
        }
        __syncthreads();   // gates ready; all hlds4 reads of step t done

        // ---- epilogue (wave 0, lanes 0-7): publish data, drain, increment ----
        if (tid < 8) {
            float iv = gates[0 * 8 + tid];
            float fv = gates[1 * 8 + tid];
            float gv = gates[2 * 8 + tid];
            float ov = gates[3 * 8 + tid];
            float cn = fsigm(fv) * c_s[tid] + fsigm(iv) * ftanh(gv);
            float hn = fsigm(ov) * ftanh(cn);
            c_s[tid] = cn;
            hlast[tid] = hn;
            __hip_atomic_store(&hdata[(size_t)(t & 1) * HDIM + b * 8 + tid], hn,
                               __ATOMIC_RELAXED, __HIP_MEMORY_SCOPE_SYSTEM);
            asm volatile("s_waitcnt vmcnt(0)" ::: "memory");   // release: data at MALL
            if (tid == 0)
                __hip_atomic_fetch_add(ctr + (size_t)(b >> 5) * CTR_STRIDE, 1u,
                                       __ATOMIC_RELAXED, __HIP_MEMORY_SCOPE_SYSTEM);
            __builtin_nontemporal_store(hn, &out[2 * HDIM + (size_t)t * HDIM + b * 8 + tid]);
        }
        // Lap-safety: block X writes hdata slot (t+1)&1 at step t+1 only after
        // ctr >= 32*(t+2), which needs every block's step-t increment, which
        // happens only after that block's step-t reads of slot (t+1)&1. QED.
    }

    if (tid < 8) {
        out[b * 8 + tid]        = c_s[tid];   // c_f
        out[HDIM + b * 8 + tid] = hlast[tid]; // h_f
    }
}

// ---------------- launch ----------------
extern "C" void kernel_launch(void* const* d_in, const int* in_sizes, int n_in,
                              void* d_out, int out_size, void* d_ws, size_t ws_size,
                              hipStream_t stream) {
    const float* x   = (const float*)d_in[0];
    const float* c0  = (const float*)d_in[1];
    const float* h0  = (const float*)d_in[2];
    const float* Wi  = (const float*)d_in[3];
    const float* Wh  = (const float*)d_in[4];
    const float* bia = (const float*)d_in[5];
    float* out = (float*)d_out;

    char* base = (char*)d_ws;
    float* Y = (float*)base;                                  // 128 MiB
    base += (size_t)T_STEPS * NG * sizeof(float);
    unsigned* ctr = (unsigned*)base;                          // 512 B
    base += 8 * CTR_STRIDE * sizeof(unsigned);
    float* hdata = (float*)base;                              // 16 KiB

    const int initN = 8 * CTR_STRIDE + 2 * HDIM;
    hipLaunchKernelGGL(init_ws4, dim3((initN + 511) / 512), dim3(512), 0, stream,
                       h0, ctr, hdata);
    hipLaunchKernelGGL(gemm_xwi, dim3(NG / 64, T_STEPS / 64), dim3(256), 0, stream,
                       x, Wi, bia, Y);

    void* args[] = { (void*)&Y, (void*)&c0, (void*)&Wh,
                     (void*)&hdata, (void*)&ctr, (void*)&out };
    hipLaunchCooperativeKernel((const void*)lstm_persistent, dim3(256), dim3(512),
                               args, 0, stream);
}